// Round 4
// baseline (233.956 us; speedup 1.0000x reference)
//
#include <hip/hip_runtime.h>
#include <math.h>

#define T_TOK 2048
#define H_DIM 1024
#define M_DIM 512
#define E_NUM 32
#define TOPK  4

#define BT  128        // tokens per tile
#define BK  32         // k per step
#define GU_BM 64       // gateup N-tile
#define DN_BH 128      // down N-tile
#define MAX_TILES 96   // sum ceil(cnt_e/128) <= 32 + 8192/128 = 96

typedef __bf16 bf16x8 __attribute__((ext_vector_type(8)));
typedef float f32x4 __attribute__((ext_vector_type(4)));
typedef unsigned short u16x8 __attribute__((ext_vector_type(8)));
typedef unsigned short u16x4 __attribute__((ext_vector_type(4)));

__device__ __forceinline__ unsigned short f2bf(float f) {
  unsigned u = __float_as_uint(f);
  return (unsigned short)((u + 0x7fffu + ((u >> 16) & 1u)) >> 16);
}
__device__ __forceinline__ float bf2f(unsigned short h) {
  return __uint_as_float(((unsigned)h) << 16);
}
__device__ __forceinline__ f32x4 mfma16(bf16x8 a, bf16x8 b, f32x4 c) {
  return __builtin_amdgcn_mfma_f32_16x16x32_bf16(a, b, c, 0, 0, 0);
}
__device__ __forceinline__ void soft_barrier() {
  // raw barrier: lgkm-only drain (LDS writes visible), in-flight VMEM keeps flying
  asm volatile("s_waitcnt lgkmcnt(0)" ::: "memory");
  __builtin_amdgcn_sched_barrier(0);
  __builtin_amdgcn_s_barrier();
  __builtin_amdgcn_sched_barrier(0);
}

// ---------------- K1: gating + x split + scatter (fused) ---------------------
__global__ __launch_bounds__(256) void gating_kernel(
    const float* __restrict__ x, const float* __restrict__ gate_w,
    unsigned short* __restrict__ xh, unsigned short* __restrict__ xl,
    float* __restrict__ topk_w, int* __restrict__ cursors,
    int* __restrict__ tok_list) {
  __shared__ float xr[H_DIM];
  __shared__ float logits[E_NUM];
  int t = blockIdx.x;
  int tid = threadIdx.x;
  const float* xrow = x + (size_t)t * H_DIM;
  float4 v = *(const float4*)(xrow + tid * 4);
  *(float4*)(xr + tid * 4) = v;
  {  // split this thread's 4 elems to hi/lo bf16
    float f[4] = {v.x, v.y, v.z, v.w};
    u16x4 hv, lv;
    #pragma unroll
    for (int j = 0; j < 4; ++j) {
      unsigned short h = f2bf(f[j]);
      hv[j] = h;
      lv[j] = f2bf(f[j] - bf2f(h));
    }
    *(u16x4*)(xh + (size_t)t * H_DIM + tid * 4) = hv;
    *(u16x4*)(xl + (size_t)t * H_DIM + tid * 4) = lv;
  }
  __syncthreads();
  int wave = tid >> 6, lane = tid & 63;
  const float4* x4 = (const float4*)xr;
  for (int e8 = 0; e8 < 8; ++e8) {
    int e = wave * 8 + e8;
    const float4* g4 = (const float4*)(gate_w + (size_t)e * H_DIM);
    float p = 0.f;
    #pragma unroll
    for (int i = 0; i < 4; ++i) {
      float4 a = x4[lane + i * 64];
      float4 b = g4[lane + i * 64];
      p += a.x * b.x + a.y * b.y + a.z * b.z + a.w * b.w;
    }
    for (int off = 32; off > 0; off >>= 1) p += __shfl_down(p, off, 64);
    if (lane == 0) logits[e] = p;
  }
  __syncthreads();
  if (tid == 0) {
    float vv[E_NUM];
    for (int e = 0; e < E_NUM; ++e) vv[e] = logits[e];
    int ids[TOPK]; float vals[TOPK];
    for (int k = 0; k < TOPK; ++k) {
      int bi = 0; float bv = -1e30f;
      for (int e = 0; e < E_NUM; ++e) if (vv[e] > bv) { bv = vv[e]; bi = e; }
      ids[k] = bi; vals[k] = bv; vv[bi] = -1e30f;
    }
    float m = vals[0];
    float w[TOPK]; float s = 0.f;
    for (int k = 0; k < TOPK; ++k) { w[k] = expf(vals[k] - m); s += w[k]; }
    float inv = 1.f / s;
    for (int k = 0; k < TOPK; ++k) {
      int g = t * TOPK + k;
      topk_w[g] = w[k] * inv;
      int slot = atomicAdd(&cursors[ids[k]], 1);
      tok_list[ids[k] * T_TOK + slot] = g;
    }
  }
}

// ---------------- K2b: tile work list ----------------------------------------
__global__ void build_tiles(const int* __restrict__ cursors,
                            int* __restrict__ n_tiles, int* __restrict__ tile_list) {
  int lane = threadIdx.x;
  int nt = 0;
  if (lane < E_NUM) nt = (cursors[lane] + BT - 1) / BT;
  int pfx = nt;
  for (int off = 1; off < 64; off <<= 1) {
    int v = __shfl_up(pfx, off, 64);
    if (lane >= off) pfx += v;
  }
  int excl = pfx - nt;
  if (lane == E_NUM - 1) *n_tiles = pfx;
  if (lane < E_NUM)
    for (int i = 0; i < nt; ++i) tile_list[excl + i] = (lane << 8) | i;
}

// ---------------- K3: gateup — dbuf LDS, 1 raw barrier per K-step ------------
// LDS layout (ushort idx): elem(row,k) at (row>>4)*512 + ((k>>3)&3)*128 + (row&15)*8 + (k&7)
// staging thread tid -> row=(tid>>6)*16+(tid&15), kq=(tid>>4)&3, LDS off = tid*8 (lane-linear)
// frag read: rows R..R+15, lane reads off = (R>>4)*512 + lane*8 (lane-linear)
__global__ __launch_bounds__(512) void gateup_mfma(
    const unsigned short* __restrict__ xh, const unsigned short* __restrict__ xl,
    const float* __restrict__ w_gate, const float* __restrict__ w_up,
    const float* __restrict__ topk_w,
    const int* __restrict__ cursors, const int* __restrict__ tok_list,
    const int* __restrict__ n_tiles, const int* __restrict__ tile_list,
    unsigned short* __restrict__ mixed) {
  if (blockIdx.y >= *n_tiles) return;
  int tid = threadIdx.x;
  int entry = tile_list[blockIdx.y];
  int e = entry >> 8, tile = entry & 255;
  int cnt = cursors[e];
  int m0 = blockIdx.x * GU_BM;

  __shared__ unsigned short Ah[2][BT * BK], Al[2][BT * BK];  // 8 KB each buf
  __shared__ unsigned short Gh[2][GU_BM * BK], Uh[2][GU_BM * BK];
  __shared__ int   ent[BT];
  __shared__ float rw[BT];

  if (tid < BT) {
    int idx = tile * BT + tid;
    int en = (idx < cnt) ? tok_list[e * T_TOK + idx] : -1;
    ent[tid] = en;
    rw[tid]  = (en >= 0) ? topk_w[en] : 0.f;
  }
  __syncthreads();

  // A staging
  int arow = ((tid >> 6) << 4) + (tid & 15);  // 0..127
  int akq  = (tid >> 4) & 3;
  int aen = ent[arow];
  if (aen < 0) aen = ent[0];  // garbage rows harmless: their out rows skipped
  const unsigned short* pAh = xh + (size_t)(aen >> 2) * H_DIM + akq * 8;
  const unsigned short* pAl = xl + (size_t)(aen >> 2) * H_DIM + akq * 8;
  int aoff = tid * 8;

  // B staging: waves 0-3 -> G, waves 4-7 -> U
  int bslot = tid & 255;
  int brow = (((bslot >> 6) & 3) << 4) + (bslot & 15);  // 0..63
  int bkq  = (bslot >> 4) & 3;
  const float* pB = ((tid < 256) ? w_gate : w_up) +
                    ((size_t)e * M_DIM + m0 + brow) * H_DIM + bkq * 8;
  int boff = bslot * 8;

  int lane = tid & 63, wid = tid >> 6;
  int wr = (wid >> 1) * 32;  // 0,32,64,96
  int wc = (wid & 1) * 32;   // 0,32
  int l16 = lane * 8;

  f32x4 accg[2][2] = {}; f32x4 accu[2][2] = {};

  u16x8 rah, ral; float bf8[8];
  // ks=0 load
  rah = *(const u16x8*)pAh;
  ral = *(const u16x8*)pAl;
  *(float4*)bf8 = *(const float4*)pB;
  *(float4*)(bf8 + 4) = *(const float4*)(pB + 4);
  {  // write buf 0
    u16x8 bh;
    #pragma unroll
    for (int j = 0; j < 8; ++j) bh[j] = f2bf(bf8[j]);
    *(u16x8*)&Ah[0][aoff] = rah;
    *(u16x8*)&Al[0][aoff] = ral;
    if (tid < 256) *(u16x8*)&Gh[0][boff] = bh;
    else           *(u16x8*)&Uh[0][boff] = bh;
  }
  __syncthreads();
  // ks=1 load (in flight across iter 0)
  rah = *(const u16x8*)(pAh + BK);
  ral = *(const u16x8*)(pAl + BK);
  *(float4*)bf8 = *(const float4*)(pB + BK);
  *(float4*)(bf8 + 4) = *(const float4*)(pB + BK + 4);

  const int NK = H_DIM / BK;
  int cur = 0;
  for (int ks = 0; ks < NK; ++ks) {
    // fragment reads from buf[cur]
    int ab = (wr >> 4) * 512 + l16;
    bf16x8 a0h = *(const bf16x8*)&Ah[cur][ab];
    bf16x8 a1h = *(const bf16x8*)&Ah[cur][ab + 512];
    bf16x8 a0l = *(const bf16x8*)&Al[cur][ab];
    bf16x8 a1l = *(const bf16x8*)&Al[cur][ab + 512];
    int nb0 = (wc >> 4) * 512 + l16;
    bf16x8 g0 = *(const bf16x8*)&Gh[cur][nb0];
    bf16x8 g1 = *(const bf16x8*)&Gh[cur][nb0 + 512];
    bf16x8 u0 = *(const bf16x8*)&Uh[cur][nb0];
    bf16x8 u1 = *(const bf16x8*)&Uh[cur][nb0 + 512];

    if (ks + 1 < NK) {
      // stage ks+1 into buf[cur^1]
      u16x8 bh;
      #pragma unroll
      for (int j = 0; j < 8; ++j) bh[j] = f2bf(bf8[j]);
      *(u16x8*)&Ah[cur ^ 1][aoff] = rah;
      *(u16x8*)&Al[cur ^ 1][aoff] = ral;
      if (tid < 256) *(u16x8*)&Gh[cur ^ 1][boff] = bh;
      else           *(u16x8*)&Uh[cur ^ 1][boff] = bh;
      if (ks + 2 < NK) {  // issue ks+2 loads (2-iteration latency window)
        int kq = (ks + 2) * BK;
        rah = *(const u16x8*)(pAh + kq);
        ral = *(const u16x8*)(pAl + kq);
        *(float4*)bf8 = *(const float4*)(pB + kq);
        *(float4*)(bf8 + 4) = *(const float4*)(pB + kq + 4);
      }
    }

    accg[0][0] = mfma16(a0h, g0, accg[0][0]);
    accg[0][0] = mfma16(a0l, g0, accg[0][0]);
    accg[1][0] = mfma16(a1h, g0, accg[1][0]);
    accg[1][0] = mfma16(a1l, g0, accg[1][0]);
    accg[0][1] = mfma16(a0h, g1, accg[0][1]);
    accg[0][1] = mfma16(a0l, g1, accg[0][1]);
    accg[1][1] = mfma16(a1h, g1, accg[1][1]);
    accg[1][1] = mfma16(a1l, g1, accg[1][1]);
    accu[0][0] = mfma16(a0h, u0, accu[0][0]);
    accu[0][0] = mfma16(a0l, u0, accu[0][0]);
    accu[1][0] = mfma16(a1h, u0, accu[1][0]);
    accu[1][0] = mfma16(a1l, u0, accu[1][0]);
    accu[0][1] = mfma16(a0h, u1, accu[0][1]);
    accu[0][1] = mfma16(a0l, u1, accu[0][1]);
    accu[1][1] = mfma16(a1h, u1, accu[1][1]);
    accu[1][1] = mfma16(a1l, u1, accu[1][1]);

    if (ks + 1 < NK) soft_barrier();
    cur ^= 1;
  }

  #pragma unroll
  for (int mf = 0; mf < 2; ++mf) {
    #pragma unroll
    for (int j = 0; j < 4; ++j) {
      int tr = wr + mf * 16 + (lane >> 4) * 4 + j;
      int en = ent[tr];
      if (en < 0) continue;
      float w = rw[tr];
      #pragma unroll
      for (int nf = 0; nf < 2; ++nf) {
        float g = accg[mf][nf][j], u = accu[mf][nf][j];
        float val = (g / (1.f + __expf(-g))) * u * w;
        mixed[(size_t)en * M_DIM + m0 + wc + nf * 16 + (lane & 15)] = f2bf(val);
      }
    }
  }
}

// ---------------- K4: down — dbuf LDS, 1 raw barrier per K-step --------------
__global__ __launch_bounds__(512) void down_mfma(
    const float* __restrict__ w_down, const unsigned short* __restrict__ mixed,
    const int* __restrict__ cursors, const int* __restrict__ tok_list,
    const int* __restrict__ n_tiles, const int* __restrict__ tile_list,
    float* __restrict__ out) {
  if (blockIdx.y >= *n_tiles) return;
  int tid = threadIdx.x;
  int entry = tile_list[blockIdx.y];
  int e = entry >> 8, tile = entry & 255;
  int cnt = cursors[e];
  int h0 = blockIdx.x * DN_BH;

  __shared__ unsigned short As[2][BT * BK];     // 8 KB each buf
  __shared__ unsigned short Bs[2][DN_BH * BK];  // 8 KB each buf
  __shared__ int ent[BT];

  if (tid < BT) {
    int idx = tile * BT + tid;
    ent[tid] = (idx < cnt) ? tok_list[e * T_TOK + idx] : -1;
  }
  __syncthreads();

  int arow = ((tid >> 6) << 4) + (tid & 15);  // 0..127
  int akq  = (tid >> 4) & 3;
  int aen = ent[arow];
  if (aen < 0) aen = ent[0];
  const unsigned short* pA = mixed + (size_t)aen * M_DIM + akq * 8;
  const float* pB = w_down + ((size_t)e * H_DIM + h0 + arow) * M_DIM + akq * 8;
  int soff = tid * 8;

  int lane = tid & 63, wid = tid >> 6;
  int wr = (wid >> 1) * 32, wc = (wid & 1) * 64;
  int l16 = lane * 8;

  f32x4 acc[2][4] = {};
  u16x8 ra; float bf8[8];
  ra = *(const u16x8*)pA;
  *(float4*)bf8 = *(const float4*)pB;
  *(float4*)(bf8 + 4) = *(const float4*)(pB + 4);
  {
    u16x8 bh;
    #pragma unroll
    for (int j = 0; j < 8; ++j) bh[j] = f2bf(bf8[j]);
    *(u16x8*)&As[0][soff] = ra;
    *(u16x8*)&Bs[0][soff] = bh;
  }
  __syncthreads();
  ra = *(const u16x8*)(pA + BK);
  *(float4*)bf8 = *(const float4*)(pB + BK);
  *(float4*)(bf8 + 4) = *(const float4*)(pB + BK + 4);

  const int NK = M_DIM / BK;
  int cur = 0;
  for (int ks = 0; ks < NK; ++ks) {
    int ab = (wr >> 4) * 512 + l16;
    bf16x8 a0 = *(const bf16x8*)&As[cur][ab];
    bf16x8 a1 = *(const bf16x8*)&As[cur][ab + 512];
    bf16x8 b0 = *(const bf16x8*)&Bs[cur][((wc >> 4) + 0) * 512 + l16];
    bf16x8 b1 = *(const bf16x8*)&Bs[cur][((wc >> 4) + 1) * 512 + l16];
    bf16x8 b2 = *(const bf16x8*)&Bs[cur][((wc >> 4) + 2) * 512 + l16];
    bf16x8 b3 = *(const bf16x8*)&Bs[cur][((wc >> 4) + 3) * 512 + l16];

    if (ks + 1 < NK) {
      u16x8 bh;
      #pragma unroll
      for (int j = 0; j < 8; ++j) bh[j] = f2bf(bf8[j]);
      *(u16x8*)&As[cur ^ 1][soff] = ra;
      *(u16x8*)&Bs[cur ^ 1][soff] = bh;
      if (ks + 2 < NK) {
        int kq = (ks + 2) * BK;
        ra = *(const u16x8*)(pA + kq);
        *(float4*)bf8 = *(const float4*)(pB + kq);
        *(float4*)(bf8 + 4) = *(const float4*)(pB + kq + 4);
      }
    }

    acc[0][0] = mfma16(a0, b0, acc[0][0]);
    acc[1][0] = mfma16(a1, b0, acc[1][0]);
    acc[0][1] = mfma16(a0, b1, acc[0][1]);
    acc[1][1] = mfma16(a1, b1, acc[1][1]);
    acc[0][2] = mfma16(a0, b2, acc[0][2]);
    acc[1][2] = mfma16(a1, b2, acc[1][2]);
    acc[0][3] = mfma16(a0, b3, acc[0][3]);
    acc[1][3] = mfma16(a1, b3, acc[1][3]);

    if (ks + 1 < NK) soft_barrier();
    cur ^= 1;
  }

  #pragma unroll
  for (int mf = 0; mf < 2; ++mf) {
    #pragma unroll
    for (int j = 0; j < 4; ++j) {
      int tr = wr + mf * 16 + (lane >> 4) * 4 + j;
      int en = ent[tr];
      if (en < 0) continue;
      int t = en >> 2;
      #pragma unroll
      for (int nf = 0; nf < 4; ++nf)
        atomicAdd(&out[(size_t)t * H_DIM + h0 + wc + nf * 16 + (lane & 15)],
                  acc[mf][nf][j]);
    }
  }
}

extern "C" void kernel_launch(void* const* d_in, const int* in_sizes, int n_in,
                              void* d_out, int out_size, void* d_ws, size_t ws_size,
                              hipStream_t stream) {
  const float* x      = (const float*)d_in[0];
  const float* gate_w = (const float*)d_in[1];
  const float* w_gate = (const float*)d_in[2];
  const float* w_up   = (const float*)d_in[3];
  const float* w_down = (const float*)d_in[4];
  float* out = (float*)d_out;

  char* ws = (char*)d_ws;
  size_t off = 0;
  float* topk_w    = (float*)(ws + off); off += (size_t)T_TOK * TOPK * 4;
  int*   cursors   = (int*)(ws + off);   off += 256;
  int*   n_tiles   = (int*)(ws + off);   off += 64;
  int*   tile_list = (int*)(ws + off);   off += MAX_TILES * 4 + 64;
  int*   tok_list  = (int*)(ws + off);   off += (size_t)E_NUM * T_TOK * 4;
  unsigned short* x_hi  = (unsigned short*)(ws + off); off += (size_t)T_TOK * H_DIM * 2;
  unsigned short* x_lo  = (unsigned short*)(ws + off); off += (size_t)T_TOK * H_DIM * 2;
  unsigned short* mixed = (unsigned short*)(ws + off); off += (size_t)T_TOK * TOPK * M_DIM * 2;

  hipMemsetAsync(cursors, 0, E_NUM * sizeof(int), stream);
  hipMemsetAsync(out, 0, (size_t)T_TOK * H_DIM * sizeof(float), stream);

  gating_kernel<<<T_TOK, 256, 0, stream>>>(x, gate_w, x_hi, x_lo, topk_w,
                                           cursors, tok_list);
  build_tiles<<<1, 64, 0, stream>>>(cursors, n_tiles, tile_list);
  gateup_mfma<<<dim3(M_DIM / GU_BM, MAX_TILES), 512, 0, stream>>>(
      x_hi, x_lo, w_gate, w_up, topk_w, cursors, tok_list, n_tiles, tile_list, mixed);
  down_mfma<<<dim3(H_DIM / DN_BH, MAX_TILES), 512, 0, stream>>>(
      w_down, mixed, cursors, tok_list, n_tiles, tile_list, out);
}